// Round 1
// baseline (44.114 us; speedup 1.0000x reference)
//
#include <hip/hip_runtime.h>

#define BATCH 65536

__device__ __forceinline__ float softplus_f(float y) {
  // log(1 + exp(y)), numerically stable
  float a = fabsf(y);
  return fmaxf(y, 0.0f) + log1pf(__expf(-a));
}

extern "C" __global__ void __launch_bounds__(256, 8)
w2v_main(const int* __restrict__ target, const int* __restrict__ pos,
         const int2* __restrict__ neg, const float4* __restrict__ w1,
         const float4* __restrict__ w2, double* __restrict__ acc)
{
  __shared__ float wsum[4];
  const int tid  = threadIdx.x;
  const int lane = tid & 63;
  const int wv   = tid >> 6;
  const int l16  = lane & 15;   // lane within 16-lane group
  const int g    = lane >> 4;   // which of 4 batch elements this group owns
  const int gw   = blockIdx.x * 4 + wv;   // global wave id
  const int nw   = gridDim.x * 4;         // total waves

  float lsum = 0.0f;
  for (int base = gw * 4; base < BATCH; base += nw * 4) {
    const int b  = base + g;
    const int t  = target[b];
    const int p  = pos[b];
    const int2 nn = neg[b];
    // Each 16-lane group reads one full 64-float row as float4/lane (256B coalesced)
    const float4 h  = w1[(long)t    * 16 + l16];
    const float4 ep = w2[(long)p    * 16 + l16];
    const float4 e0 = w2[(long)nn.x * 16 + l16];
    const float4 e1 = w2[(long)nn.y * 16 + l16];

    float ps = h.x * ep.x + h.y * ep.y + h.z * ep.z + h.w * ep.w;
    float sx = e0.x + e1.x, sy = e0.y + e1.y, sz = e0.z + e1.z, sw = e0.w + e1.w;
    float nd = h.x * sx + h.y * sy + h.z * sz + h.w * sw;  // = -neg_score

    // reduce across the 16-lane group (all lanes end with group total)
    #pragma unroll
    for (int off = 8; off; off >>= 1) {
      ps += __shfl_xor(ps, off);
      nd += __shfl_xor(nd, off);
    }
    if (l16 == 0) {
      // loss_b = softplus(-pos_score) + softplus(-neg_score)
      lsum += softplus_f(-ps) + softplus_f(nd);
    }
  }

  // fold the 4 group-leader lanes (0,16,32,48) of this wave
  lsum += __shfl_xor(lsum, 16);
  lsum += __shfl_xor(lsum, 32);
  if (lane == 0) wsum[wv] = lsum;
  __syncthreads();
  if (tid == 0) {
    float s = wsum[0] + wsum[1] + wsum[2] + wsum[3];
    atomicAdd(acc, (double)s);
  }
}

extern "C" __global__ void w2v_final(const double* __restrict__ acc, float* __restrict__ out) {
  out[0] = (float)(*acc * (1.0 / (double)BATCH));
}

extern "C" void kernel_launch(void* const* d_in, const int* in_sizes, int n_in,
                              void* d_out, int out_size, void* d_ws, size_t ws_size,
                              hipStream_t stream) {
  const int*    target = (const int*)d_in[0];
  const int*    pos    = (const int*)d_in[1];
  const int2*   neg    = (const int2*)d_in[2];
  const float4* w1     = (const float4*)d_in[3];
  const float4* w2     = (const float4*)d_in[4];
  double* acc = (double*)d_ws;
  float*  out = (float*)d_out;

  hipMemsetAsync(acc, 0, sizeof(double), stream);
  w2v_main<<<2048, 256, 0, stream>>>(target, pos, neg, w1, w2, acc);
  w2v_final<<<1, 1, 0, stream>>>(acc, out);
}

// Round 2
// 21.618 us; speedup vs baseline: 2.0406x; 2.0406x over previous
//
#include <hip/hip_runtime.h>

#define BATCH 65536
#define NBLOCKS 2048

__device__ __forceinline__ float softplus_f(float y) {
  // log(1 + exp(y)), numerically stable
  float a = fabsf(y);
  return fmaxf(y, 0.0f) + log1pf(__expf(-a));
}

// One wave owns 8 batch elements: 4 16-lane groups x 2 elements each.
// All index loads issued first, then all 8 row-gathers in flight together.
extern "C" __global__ void __launch_bounds__(256, 8)
w2v_main(const int* __restrict__ target, const int* __restrict__ pos,
         const int2* __restrict__ neg, const float4* __restrict__ w1,
         const float4* __restrict__ w2, float* __restrict__ partial)
{
  __shared__ float wsum[4];
  const int tid  = threadIdx.x;
  const int lane = tid & 63;
  const int wv   = tid >> 6;
  const int l16  = lane & 15;   // lane within 16-lane group
  const int g    = lane >> 4;   // group id within wave
  const int gw   = blockIdx.x * 4 + wv;   // global wave id (8192 total)

  const int b0 = gw * 8 + g;    // first element of this group
  const int b1 = b0 + 4;        // second element

  // ---- all index loads up front (independent) ----
  const int  t0 = target[b0], t1 = target[b1];
  const int  p0 = pos[b0],    p1 = pos[b1];
  const int2 n0 = neg[b0],    n1 = neg[b1];

  // ---- all 8 row gathers in flight (256B coalesced per 16-lane group) ----
  const float4 h0  = w1[(long)t0  * 16 + l16];
  const float4 h1  = w1[(long)t1  * 16 + l16];
  const float4 ep0 = w2[(long)p0  * 16 + l16];
  const float4 ep1 = w2[(long)p1  * 16 + l16];
  const float4 a0  = w2[(long)n0.x * 16 + l16];
  const float4 a1  = w2[(long)n0.y * 16 + l16];
  const float4 c0  = w2[(long)n1.x * 16 + l16];
  const float4 c1  = w2[(long)n1.y * 16 + l16];

  float ps0 = h0.x*ep0.x + h0.y*ep0.y + h0.z*ep0.z + h0.w*ep0.w;
  float ps1 = h1.x*ep1.x + h1.y*ep1.y + h1.z*ep1.z + h1.w*ep1.w;
  float nd0 = h0.x*(a0.x+a1.x) + h0.y*(a0.y+a1.y) + h0.z*(a0.z+a1.z) + h0.w*(a0.w+a1.w);
  float nd1 = h1.x*(c0.x+c1.x) + h1.y*(c0.y+c1.y) + h1.z*(c0.z+c1.z) + h1.w*(c0.w+c1.w);

  // reduce across the 16-lane group
  #pragma unroll
  for (int off = 8; off; off >>= 1) {
    ps0 += __shfl_xor(ps0, off);
    nd0 += __shfl_xor(nd0, off);
    ps1 += __shfl_xor(ps1, off);
    nd1 += __shfl_xor(nd1, off);
  }

  float lsum = 0.0f;
  if (l16 == 0)
    lsum = softplus_f(-ps0) + softplus_f(nd0) + softplus_f(-ps1) + softplus_f(nd1);

  // fold the 4 group-leader lanes (0,16,32,48)
  lsum += __shfl_xor(lsum, 16);
  lsum += __shfl_xor(lsum, 32);
  if (lane == 0) wsum[wv] = lsum;
  __syncthreads();
  if (tid == 0) partial[blockIdx.x] = wsum[0] + wsum[1] + wsum[2] + wsum[3];
}

extern "C" __global__ void __launch_bounds__(256)
w2v_reduce(const float* __restrict__ partial, float* __restrict__ out)
{
  __shared__ double ssum[4];
  const int tid = threadIdx.x;
  double s = 0.0;
  for (int i = tid; i < NBLOCKS; i += 256) s += (double)partial[i];
  #pragma unroll
  for (int off = 32; off; off >>= 1) s += __shfl_xor(s, off);
  if ((tid & 63) == 0) ssum[tid >> 6] = s;
  __syncthreads();
  if (tid == 0)
    out[0] = (float)((ssum[0] + ssum[1] + ssum[2] + ssum[3]) * (1.0 / (double)BATCH));
}

extern "C" void kernel_launch(void* const* d_in, const int* in_sizes, int n_in,
                              void* d_out, int out_size, void* d_ws, size_t ws_size,
                              hipStream_t stream) {
  const int*    target = (const int*)d_in[0];
  const int*    pos    = (const int*)d_in[1];
  const int2*   neg    = (const int2*)d_in[2];
  const float4* w1     = (const float4*)d_in[3];
  const float4* w2     = (const float4*)d_in[4];
  float* partial = (float*)d_ws;
  float* out     = (float*)d_out;

  w2v_main<<<NBLOCKS, 256, 0, stream>>>(target, pos, neg, w1, w2, partial);
  w2v_reduce<<<1, 256, 0, stream>>>(partial, out);
}

// Round 3
// 19.946 us; speedup vs baseline: 2.2116x; 1.0838x over previous
//
#include <hip/hip_runtime.h>

#define BATCH 65536
#define NBLOCKS 2048
#define NWAVES (NBLOCKS * 4)   // 8192 per-wave partials

__device__ __forceinline__ float softplus_f(float y) {
  // log(1 + exp(y)), numerically stable
  float a = fabsf(y);
  return fmaxf(y, 0.0f) + log1pf(__expf(-a));
}

// One wave owns 8 batch elements: 4 16-lane groups x 2 elements each.
// All index loads issued first, then all 8 row-gathers in flight together.
// No LDS, no barrier: lane 0 writes one per-wave partial.
extern "C" __global__ void __launch_bounds__(256, 8)
w2v_main(const int* __restrict__ target, const int* __restrict__ pos,
         const int2* __restrict__ neg, const float4* __restrict__ w1,
         const float4* __restrict__ w2, float* __restrict__ partial)
{
  const int tid  = threadIdx.x;
  const int lane = tid & 63;
  const int wv   = tid >> 6;
  const int l16  = lane & 15;   // lane within 16-lane group
  const int g    = lane >> 4;   // group id within wave
  const int gw   = blockIdx.x * 4 + wv;   // global wave id (8192 total)

  const int b0 = gw * 8 + g;    // first element of this group
  const int b1 = b0 + 4;        // second element

  // ---- all index loads up front (independent) ----
  const int  t0 = target[b0], t1 = target[b1];
  const int  p0 = pos[b0],    p1 = pos[b1];
  const int2 n0 = neg[b0],    n1 = neg[b1];

  // ---- all 8 row gathers in flight (256B coalesced per 16-lane group) ----
  // 32-bit element offsets: max index 1855601*16+15 < 2^25, fits easily.
  const float4 h0  = w1[((unsigned)t0  << 4) + l16];
  const float4 h1  = w1[((unsigned)t1  << 4) + l16];
  const float4 ep0 = w2[((unsigned)p0  << 4) + l16];
  const float4 ep1 = w2[((unsigned)p1  << 4) + l16];
  const float4 a0  = w2[((unsigned)n0.x << 4) + l16];
  const float4 a1  = w2[((unsigned)n0.y << 4) + l16];
  const float4 c0  = w2[((unsigned)n1.x << 4) + l16];
  const float4 c1  = w2[((unsigned)n1.y << 4) + l16];

  float ps0 = h0.x*ep0.x + h0.y*ep0.y + h0.z*ep0.z + h0.w*ep0.w;
  float ps1 = h1.x*ep1.x + h1.y*ep1.y + h1.z*ep1.z + h1.w*ep1.w;
  float nd0 = h0.x*(a0.x+a1.x) + h0.y*(a0.y+a1.y) + h0.z*(a0.z+a1.z) + h0.w*(a0.w+a1.w);
  float nd1 = h1.x*(c0.x+c1.x) + h1.y*(c0.y+c1.y) + h1.z*(c0.z+c1.z) + h1.w*(c0.w+c1.w);

  // reduce across the 16-lane group
  #pragma unroll
  for (int off = 8; off; off >>= 1) {
    ps0 += __shfl_xor(ps0, off);
    nd0 += __shfl_xor(nd0, off);
    ps1 += __shfl_xor(ps1, off);
    nd1 += __shfl_xor(nd1, off);
  }

  float lsum = 0.0f;
  if (l16 == 0)
    lsum = softplus_f(-ps0) + softplus_f(nd0) + softplus_f(-ps1) + softplus_f(nd1);

  // fold the 4 group-leader lanes (0,16,32,48) and write one partial per wave
  lsum += __shfl_xor(lsum, 16);
  lsum += __shfl_xor(lsum, 32);
  if (lane == 0) partial[gw] = lsum;
}

// Single-wave finalize: 8192 floats = 2048 float4, 32 per lane (L2-resident).
extern "C" __global__ void __launch_bounds__(64)
w2v_reduce(const float4* __restrict__ partial4, float* __restrict__ out)
{
  const int lane = threadIdx.x;
  double s = 0.0;
  #pragma unroll
  for (int i = 0; i < 32; ++i) {
    float4 v = partial4[lane + i * 64];
    s += (double)((v.x + v.y) + (v.z + v.w));
  }
  #pragma unroll
  for (int off = 32; off; off >>= 1) s += __shfl_xor(s, off);
  if (lane == 0) out[0] = (float)(s * (1.0 / (double)BATCH));
}

extern "C" void kernel_launch(void* const* d_in, const int* in_sizes, int n_in,
                              void* d_out, int out_size, void* d_ws, size_t ws_size,
                              hipStream_t stream) {
  const int*    target = (const int*)d_in[0];
  const int*    pos    = (const int*)d_in[1];
  const int2*   neg    = (const int2*)d_in[2];
  const float4* w1     = (const float4*)d_in[3];
  const float4* w2     = (const float4*)d_in[4];
  float* partial = (float*)d_ws;
  float* out     = (float*)d_out;

  w2v_main<<<NBLOCKS, 256, 0, stream>>>(target, pos, neg, w1, w2, partial);
  w2v_reduce<<<1, 64, 0, stream>>>((const float4*)partial, out);
}